// Round 2
// baseline (818.709 us; speedup 1.0000x reference)
//
#include <hip/hip_runtime.h>
#include <hip/hip_bf16.h>

// Problem constants
#define BB 32    // batch
#define TT 128   // T_E == T_D
#define HH 256   // hidden
#define G4 4     // blocks per batch for LSTM
#define UPB 64   // units per LSTM slice (256/4)

#define AGENT __HIP_MEMORY_SCOPE_AGENT
#define AL(p) __hip_atomic_load((p), __ATOMIC_RELAXED, AGENT)

__device__ __forceinline__ float rcp_f(float x) { return __builtin_amdgcn_rcpf(x); }
__device__ __forceinline__ float sigmoid_f(float x) {
    return rcp_f(1.f + __expf(-x));  // ~1e-7 rel err vs 7e-3 threshold
}
__device__ __forceinline__ float tanh_f(float x) {
    float e = __expf(2.f * x);
    return 1.f - 2.f * rcp_f(e + 1.f);
}

// LDS-only barrier (R16: proven neutral vs __syncthreads, semantically sufficient).
__device__ __forceinline__ void bar_lds() {
    asm volatile("s_waitcnt lgkmcnt(0)\n\ts_barrier" ::: "memory");
}

// ---------------------------------------------------------------------------
// LSTM + fused projections — R17 gate-colocated layout.
// grid = 128 (blk = g*32 + b); block = 512 = 8 waves.
// R17 change vs R12/R15/R16 structure: unit u's 4 gates x 2 k-halves live on
// 8 ADJACENT LANES of one wave (tid = u*8 + j; gate=j>>1, half=j&1). Gate
// combine = 3 shfl_xor instead of g_lds store -> barrier A -> load. Leader
// lanes (j==0, 8/wave) hold c state, run activations, publish. Barrier A is
// DELETED: one barrier per step (end-of-step barrier alone separates hbuf
// epochs: step t writes the buffer step t-1 read).
// Roles after the leader segment: waves 0-2 poll partners (tid<192, 1 value
// each), wave 3 idle, waves 4-7 proj e2/d2 row t-1 (unchanged R12 projdot).
// Measured ledger:
//   R12 plain (4-way-conflicted proj): lstm 545us
//   R13 pw[runtime idx]: scratch demotion, 1449us  -> keep static offsets
//   R14 rotated address: conflict-free but +addr-VALU in slot, 645us
//   R15: lstm 484us  |  R16 lgkmcnt-only barriers: 485us (NULL -> vmcnt
//        drain was never on the critical path)
// ---------------------------------------------------------------------------
__global__ __launch_bounds__(512, 2) void lstm_kernel(
    const float* __restrict__ seq,     // [B][128]
    const int* __restrict__ seq_m,     // [B]
    const float* __restrict__ target,  // [B][128]
    const float* __restrict__ Wih_e,   // [1024]
    const float* __restrict__ Whh_e,   // [1024][256]
    const float* __restrict__ bih_e, const float* __restrict__ bhh_e,
    const float* __restrict__ Wih_d, const float* __restrict__ Whh_d,
    const float* __restrict__ bih_d, const float* __restrict__ bhh_d,
    const float* __restrict__ We, const float* __restrict__ be,
    const float* __restrict__ Wd, const float* __restrict__ bd,
    float* __restrict__ e2,  // [B][128][256]
    float* __restrict__ d2,  // [B][128][256]
    unsigned long long* __restrict__ mbox,   // [2][B][256] tagged h packets
    unsigned long long* __restrict__ hsave)  // [B][256] tag-1 enc state @ last
{
    const int blk = blockIdx.x;
    const int b = blk & 31;   // batch
    const int g = blk >> 5;   // slice 0..3
    const int tid = threadIdx.x;
    const int u = tid >> 3;   // local unit 0..63 (wave w owns units 8w..8w+7)
    const int j8 = tid & 7;   // role within unit: gate = j8>>1, half = j8&1
    const int gate = j8 >> 1;
    const int half = j8 & 1;
    const int row_global = gate * HH + g * UPB + u;
    const int ug = g * UPB + u;  // global unit index (leader lanes)
    const int last = seq_m[b] - 1;
    // proj role (waves 4-7): s in [0,256); col g*64+(s>>2); k-quarter s&3
    const int s = tid - 256;
    const int pu = s >> 2;
    const int kq = s & 3;
    const int pcol = g * UPB + pu;

    __shared__ float hbuf[2][HH];   // double-buffered h (dot reads ^1)
    __shared__ float x_lds[2 * TT];
    __shared__ float h_final[HH];   // boundary h vector

    for (int i = tid; i < TT; i += 512) {
        x_lds[i] = seq[b * TT + i];
        x_lds[TT + i] = target[b * TT + i];
    }

    float4 w[32];
    float bias_r, wih_r;
    auto loadw = [&](const float* Whh, const float* Wih,
                     const float* bih, const float* bhh) {
        const float4* wr = (const float4*)(Whh + row_global * HH + half * 128);
#pragma unroll
        for (int i = 0; i < 32; ++i) w[i] = wr[i];
        bias_r = bih[row_global] + bhh[row_global];
        wih_r = Wih[row_global];
    };
    loadw(Whh_e, Wih_e, bih_e, bhh_e);

    float4 pw[16];
    float pb = 0.f;
    auto loadp = [&](const float* W, const float* bias) {
        const float4* src = (const float4*)(W + pcol * HH + kq * 64);
#pragma unroll
        for (int i = 0; i < 16; ++i) pw[i] = src[i];
        pb = bias[pcol];
    };
    if (tid >= 256) loadp(We, be);

    // plain proj dot: static offsets, no extra address VALU (R12-proven)
    auto projdot = [&](const float* hsrc) -> float {
        const float4* hp = (const float4*)(hsrc + kq * 64);
        float pa = 0.f;
#pragma unroll
        for (int i = 0; i < 16; ++i) {
            float4 hv = hp[i];
            pa = fmaf(pw[i].x, hv.x, pa);
            pa = fmaf(pw[i].y, hv.y, pa);
            pa = fmaf(pw[i].z, hv.z, pa);
            pa = fmaf(pw[i].w, hv.w, pa);
        }
        pa += __shfl_xor(pa, 1);
        pa += __shfl_xor(pa, 2);  // 4 k-quarters combined
        return pa + pb;
    };

    if (tid < 64) {  // h(-1) = 0 lives in buffer 1
        ((float4*)hbuf[1])[tid] = make_float4(0.f, 0.f, 0.f, 0.f);
    }
    __syncthreads();

    float c = 0.f, c_saved = 0.f, h_saved = 0.f;

    for (int t = 0; t < 2 * TT; ++t) {
        const int phase = t >> 7;  // 0 = encoder, 1 = decoder
        const int tt = t & 127;
        const float x = x_lds[t];
        const int rb = (t & 1) ^ 1;  // buffer holding h(t-1)

        // ---- phase 1 (all 8 waves): gate-row dot over own 128-wide slice --
        const float4* h4 = ((const float4*)hbuf[rb]) + half * 32;
        float4 a4 = make_float4(0.f, 0.f, 0.f, 0.f);
#pragma unroll
        for (int i = 0; i < 32; ++i) {
            float4 hv = h4[i];
            a4.x = fmaf(w[i].x, hv.x, a4.x);
            a4.y = fmaf(w[i].y, hv.y, a4.y);
            a4.z = fmaf(w[i].z, hv.z, a4.z);
            a4.w = fmaf(w[i].w, hv.w, a4.w);
        }
        float acc = (a4.x + a4.y) + (a4.z + a4.w);
        acc += __shfl_xor(acc, 1);            // combine the two k-halves
        float gv = acc + bias_r + x * wih_r;  // full gate pre-activation
        // gate combine via intra-8-lane shuffles (replaces g_lds + barrier A)
        float x2v = __shfl_xor(gv, 2);   // @j8=0: f
        float x4v = __shfl_xor(gv, 4);   // @j8=0: g
        float x6v = __shfl_xor(x2v, 4);  // @j8=0: o

        // ---- phase 2 (leader lanes j8==0, 8 per wave): serial segment ----
        if (j8 == 0) {
            float si = sigmoid_f(gv);
            float sf = sigmoid_f(x2v);
            float tg = tanh_f(x4v);
            float so = sigmoid_f(x6v);
            c = sf * c + si * tg;
            float h = so * tanh_f(c);
            // publish FIRST: get the store into L2 before anything else
            unsigned long long pkt =
                ((unsigned long long)(unsigned)(t + 1) << 32) | __float_as_uint(h);
            __hip_atomic_store(&mbox[(t & 1) * BB * HH + b * HH + ug], pkt,
                               __ATOMIC_RELAXED, AGENT);
            if (phase == 0 && tt == last) {
                c_saved = c;
                h_saved = h;
                unsigned long long spkt =
                    (1ull << 32) | (unsigned long long)__float_as_uint(h);
                __hip_atomic_store(&hsave[b * HH + ug], spkt, __ATOMIC_RELAXED, AGENT);
            }
            hbuf[t & 1][ug] = (t == TT - 1) ? h_saved : h;
        }

        // ---- phase 3 (waves 0-2): ring poll of partners' tagged h ----
        if (tid < 192) {
            const int p = (g + 1 + (tid >> 6)) & 3;  // partner slice 1..3 away
            const int lane = tid & 63;
            const int ppu = p * UPB + lane;
            unsigned long long* src;
            unsigned want;
            if (t == TT - 1) {
                src = &hsave[b * HH + ppu];
                want = 1u;
            } else {
                src = &mbox[(t & 1) * BB * HH + b * HH + ppu];
                want = (unsigned)(t + 1);
            }
            unsigned long long pv;
            {
                unsigned long long r0 = AL(src);
                unsigned long long r1 = AL(src);
                unsigned long long r2 = AL(src);
                unsigned long long r3 = AL(src);
                for (;;) {
                    if ((unsigned)(r0 >> 32) == want) { pv = r0; break; }
                    r0 = AL(src);
                    if ((unsigned)(r1 >> 32) == want) { pv = r1; break; }
                    r1 = AL(src);
                    if ((unsigned)(r2 >> 32) == want) { pv = r2; break; }
                    r2 = AL(src);
                    if ((unsigned)(r3 >> 32) == want) { pv = r3; break; }
                    r3 = AL(src);
                }
            }
            hbuf[t & 1][ppu] = __uint_as_float((unsigned)pv);
        }

        // ---- proj (waves 4..7): e2/d2 row t-1, hidden in the poll window --
        if (tid >= 256 && t >= 1) {
            const float* hsrc = (t == TT) ? h_final : hbuf[rb];
            float pv = projdot(hsrc);
            if (kq == 0) {
                if (t <= TT)
                    e2[(b * TT + (t - 1)) * HH + pcol] = pv;
                else
                    d2[(b * TT + (t - 1 - TT)) * HH + pcol] = pv;
            }
        }
        // at the enc boundary, recover full h(TT-1) (tag TT) into h_final
        if (tid >= 256 && t == TT - 1) {
            unsigned long long* src = &mbox[((TT - 1) & 1) * BB * HH + b * HH + s];
            const unsigned want = (unsigned)TT;
            unsigned long long r0 = AL(src);
            unsigned long long r1 = AL(src);
            unsigned long long pv;
            for (;;) {
                if ((unsigned)(r0 >> 32) == want) { pv = r0; break; }
                r0 = AL(src);
                if ((unsigned)(r1 >> 32) == want) { pv = r1; break; }
                r1 = AL(src);
            }
            h_final[s] = __uint_as_float((unsigned)pv);
        }
        if (tid >= 256 && t == TT) loadp(Wd, bd);

        bar_lds();  // single per-step barrier: hbuf[t&1] complete for next dot

        if (t == TT - 1) {  // encoder -> decoder transition
            loadw(Whh_d, Wih_d, bih_d, bhh_d);
            c = c_saved;
        }
    }

    // ---- post-loop: d2 row TT-1 from h(2TT-1) (tag 2TT) ----
    if (tid >= 256) {
        unsigned long long* src = &mbox[((2 * TT - 1) & 1) * BB * HH + b * HH + s];
        const unsigned want = (unsigned)(2 * TT);
        unsigned long long r0 = AL(src);
        unsigned long long r1 = AL(src);
        unsigned long long pv;
        for (;;) {
            if ((unsigned)(r0 >> 32) == want) { pv = r0; break; }
            r0 = AL(src);
            if ((unsigned)(r1 >> 32) == want) { pv = r1; break; }
            r1 = AL(src);
        }
        h_final[s] = __uint_as_float((unsigned)pv);
    }
    __syncthreads();
    if (tid >= 256) {
        float pv = projdot(h_final);
        if (kq == 0) d2[(b * TT + (TT - 1)) * HH + pcol] = pv;
    }
}

// ---------------------------------------------------------------------------
// Attention scores: p = tanh(e2_j + d2_i) . v  for a 32x32 (i,j) tile.
// grid = 512 = b(32) x it(4) x jt(4); block = 256; 4x i-register-blocked.
// ---------------------------------------------------------------------------
#define EPAD 260  // float4-aligned LDS row stride
__global__ __launch_bounds__(256) void attn_p_kernel(
    const float* __restrict__ e2, const float* __restrict__ d2,
    const float* __restrict__ vv, float* __restrict__ p_ws) {
    __shared__ float e2c[32][EPAD];
    __shared__ float d2t[32][EPAD];
    __shared__ float v_lds[HH];

    const int blk = blockIdx.x;
    const int b = blk >> 4;
    const int i0 = ((blk >> 2) & 3) * 32;
    const int j0 = (blk & 3) * 32;
    const int tid = threadIdx.x;
    const int jl = tid & 31, ig = tid >> 5;

    if (tid < 64) *(float4*)&v_lds[tid * 4] = ((const float4*)vv)[tid];
    for (int idx = tid; idx < 32 * 64; idx += 256) {
        int r = idx >> 6, q = idx & 63;
        *(float4*)&d2t[r][q * 4] = ((const float4*)(d2 + (b * TT + i0 + r) * HH))[q];
        *(float4*)&e2c[r][q * 4] = ((const float4*)(e2 + (b * TT + j0 + r) * HH))[q];
    }
    __syncthreads();

    float a0 = 0.f, a1 = 0.f, a2 = 0.f, a3 = 0.f;
    for (int h = 0; h < HH; h += 4) {
        float4 ev = *(const float4*)&e2c[jl][h];
        float4 vx = *(const float4*)&v_lds[h];
        float4 d0 = *(const float4*)&d2t[ig * 4 + 0][h];
        float4 d1 = *(const float4*)&d2t[ig * 4 + 1][h];
        float4 d2v = *(const float4*)&d2t[ig * 4 + 2][h];
        float4 d3 = *(const float4*)&d2t[ig * 4 + 3][h];
        a0 = fmaf(tanh_f(ev.x + d0.x), vx.x, a0);
        a0 = fmaf(tanh_f(ev.y + d0.y), vx.y, a0);
        a0 = fmaf(tanh_f(ev.z + d0.z), vx.z, a0);
        a0 = fmaf(tanh_f(ev.w + d0.w), vx.w, a0);
        a1 = fmaf(tanh_f(ev.x + d1.x), vx.x, a1);
        a1 = fmaf(tanh_f(ev.y + d1.y), vx.y, a1);
        a1 = fmaf(tanh_f(ev.z + d1.z), vx.z, a1);
        a1 = fmaf(tanh_f(ev.w + d1.w), vx.w, a1);
        a2 = fmaf(tanh_f(ev.x + d2v.x), vx.x, a2);
        a2 = fmaf(tanh_f(ev.y + d2v.y), vx.y, a2);
        a2 = fmaf(tanh_f(ev.z + d2v.z), vx.z, a2);
        a2 = fmaf(tanh_f(ev.w + d2v.w), vx.w, a2);
        a3 = fmaf(tanh_f(ev.x + d3.x), vx.x, a3);
        a3 = fmaf(tanh_f(ev.y + d3.y), vx.y, a3);
        a3 = fmaf(tanh_f(ev.z + d3.z), vx.z, a3);
        a3 = fmaf(tanh_f(ev.w + d3.w), vx.w, a3);
    }
    float* pr = p_ws + (b * TT + i0 + ig * 4) * TT + j0 + jl;
    pr[0 * TT] = a0;
    pr[1 * TT] = a1;
    pr[2 * TT] = a2;
    pr[3 * TT] = a3;
}

// ---------------------------------------------------------------------------
// Softmax over j with mask (memory-bound finisher).
// grid = 256 = b(32) x 8 row-tiles (16 rows); block = 256 (16 rows x 16 lanes).
// ---------------------------------------------------------------------------
__global__ __launch_bounds__(256) void attn_sm_kernel(
    const float* __restrict__ p_ws, const float* __restrict__ seq,
    float* __restrict__ out) {
    const int blk = blockIdx.x;
    const int b = blk >> 3;
    const int r0 = (blk & 7) * 16;
    const int tid = threadIdx.x;
    const int r = tid >> 4, l16 = tid & 15;
    const int row = (b * TT + r0 + r) * TT;

    float xr[8];
    float m = -1e30f;
#pragma unroll
    for (int k = 0; k < 8; ++k) {
        const int j = l16 + 16 * k;
        float x = p_ws[row + j];
        float sv = (j == 0) ? 0.1f : seq[b * TT + j];
        if (sv == 0.f) x -= 1000.f;
        xr[k] = x;
        m = fmaxf(m, x);
    }
#pragma unroll
    for (int o = 8; o >= 1; o >>= 1) m = fmaxf(m, __shfl_xor(m, o));
    float s = 0.f;
#pragma unroll
    for (int k = 0; k < 8; ++k) {
        xr[k] = __expf(xr[k] - m);
        s += xr[k];
    }
#pragma unroll
    for (int o = 8; o >= 1; o >>= 1) s += __shfl_xor(s, o);
    float inv = rcp_f(s);
#pragma unroll
    for (int k = 0; k < 8; ++k) out[row + l16 + 16 * k] = xr[k] * inv;
}

// ---------------------------------------------------------------------------
extern "C" void kernel_launch(void* const* d_in, const int* in_sizes, int n_in,
                              void* d_out, int out_size, void* d_ws, size_t ws_size,
                              hipStream_t stream) {
    const float* seq = (const float*)d_in[0];
    const int* seq_m = (const int*)d_in[1];
    const float* target = (const float*)d_in[2];
    const float* Wih_e = (const float*)d_in[3];
    const float* Whh_e = (const float*)d_in[4];
    const float* bih_e = (const float*)d_in[5];
    const float* bhh_e = (const float*)d_in[6];
    const float* Wih_d = (const float*)d_in[7];
    const float* Whh_d = (const float*)d_in[8];
    const float* bih_d = (const float*)d_in[9];
    const float* bhh_d = (const float*)d_in[10];
    const float* We = (const float*)d_in[11];
    const float* be = (const float*)d_in[12];
    const float* Wd = (const float*)d_in[13];
    const float* bd = (const float*)d_in[14];
    const float* vv = (const float*)d_in[15];

    float* ws = (float*)d_ws;
    const size_t SZ_ED = (size_t)BB * TT * HH;  // 1,048,576 floats
    float* e2 = ws;
    float* d2 = e2 + SZ_ED;
    float* p_ws = d2 + SZ_ED;                               // [B][128][128]
    unsigned long long* mbox =
        (unsigned long long*)(p_ws + (size_t)BB * TT * TT);  // [2][B][H]
    unsigned long long* hsave = mbox + 2 * BB * HH;          // [B][H]

    const size_t needed = (2 * SZ_ED + (size_t)BB * TT * TT) * sizeof(float) +
                          3 * BB * HH * sizeof(unsigned long long);
    if (ws_size < needed) return;

    hipMemsetAsync(mbox, 0, 3 * BB * HH * sizeof(unsigned long long), stream);
    lstm_kernel<<<BB * G4, 512, 0, stream>>>(seq, seq_m, target, Wih_e, Whh_e, bih_e,
                                             bhh_e, Wih_d, Whh_d, bih_d, bhh_d, We,
                                             be, Wd, bd, e2, d2, mbox, hsave);
    attn_p_kernel<<<512, 256, 0, stream>>>(e2, d2, vv, p_ws);
    attn_sm_kernel<<<256, 256, 0, stream>>>(p_ws, seq, (float*)d_out);
}

// Round 3
// 638.162 us; speedup vs baseline: 1.2829x; 1.2829x over previous
//
#include <hip/hip_runtime.h>
#include <hip/hip_bf16.h>

// Problem constants
#define BB 32    // batch
#define TT 128   // T_E == T_D
#define HH 256   // hidden
#define G4 4     // blocks per batch for LSTM
#define UPB 64   // units per LSTM slice (256/4)
#define RPB 256  // gate rows per LSTM slice (4 gates * 64 units)

#define AGENT __HIP_MEMORY_SCOPE_AGENT
#define AL(p) __hip_atomic_load((p), __ATOMIC_RELAXED, AGENT)

typedef __attribute__((ext_vector_type(2))) float f32x2;

__device__ __forceinline__ float rcp_f(float x) { return __builtin_amdgcn_rcpf(x); }
__device__ __forceinline__ float sigmoid_f(float x) {
    return rcp_f(1.f + __expf(-x));  // ~1e-7 rel err vs 7e-3 threshold
}
__device__ __forceinline__ float tanh_f(float x) {
    float e = __expf(2.f * x);
    return 1.f - 2.f * rcp_f(e + 1.f);
}

// LDS-only barrier (R16: measured neutral vs __syncthreads; semantically
// sufficient — hbuf/g_lds only need lgkmcnt; mbox is tag-polled).
__device__ __forceinline__ void bar_lds() {
    asm volatile("s_waitcnt lgkmcnt(0)\n\ts_barrier" ::: "memory");
}

// ---------------------------------------------------------------------------
// LSTM + fused projections — R18 = R15 structure reverted + pk_fma gate dot
// + 6-deep poll rotation.
// grid = 128 (blk = g*32 + b); block = 512 = 8 waves.
// Waves 0-7: gate dot; wave 0: serial activation+publish; waves 1-3: ring
// poll; waves 4-7: e2/d2 proj row t-1 from double-buffered hbuf.
// Measured ledger:
//   R12 plain proj (4-way-conflicted): lstm 545us
//   R13 pw[runtime idx]: scratch demotion, 1449us  -> static offsets only
//   R14 rotated address: conflict-free but +addr-VALU in slot, 645us
//   R15: lstm 484us  |  R16 lgkmcnt-only barrier: 485us (NULL)
//   R17 gate-colocation (no barA): 706us — act/publish on every wave's
//       path + chunk completion gated on last-of-8 dots. REVERTED.
// R18 changes (cycle-shortening only, structure untouched):
//   (a) gate dot via v_pk_fma_f32 (VOP3P, 2 FMA/inst — the 157TF f32 path):
//       128 -> 64 VALU insts/wave/step on the serial cycle's dot wall.
//       w kept as float2[64] filled by identical float4 loads (no v_movs),
//       hv via one ds_read_b128 reinterpreted as two pairs, static idx only.
//   (b) poll rotation 4 -> 6 outstanding loads (detect lag ~lat/6).
//   projdot deliberately untouched (off-cycle; R13/R14 perturbation risk).
// ---------------------------------------------------------------------------
__global__ __launch_bounds__(512, 2) void lstm_kernel(
    const float* __restrict__ seq,     // [B][128]
    const int* __restrict__ seq_m,     // [B]
    const float* __restrict__ target,  // [B][128]
    const float* __restrict__ Wih_e,   // [1024]
    const float* __restrict__ Whh_e,   // [1024][256]
    const float* __restrict__ bih_e, const float* __restrict__ bhh_e,
    const float* __restrict__ Wih_d, const float* __restrict__ Whh_d,
    const float* __restrict__ bih_d, const float* __restrict__ bhh_d,
    const float* __restrict__ We, const float* __restrict__ be,
    const float* __restrict__ Wd, const float* __restrict__ bd,
    float* __restrict__ e2,  // [B][128][256]
    float* __restrict__ d2,  // [B][128][256]
    unsigned long long* __restrict__ mbox,   // [2][B][256] tagged h packets
    unsigned long long* __restrict__ hsave)  // [B][256] tag-1 enc state @ last
{
    const int blk = blockIdx.x;
    const int b = blk & 31;   // batch
    const int g = blk >> 5;   // slice 0..3
    const int tid = threadIdx.x;
    const int row_local = tid >> 1;  // 0..255
    const int half = tid & 1;        // k-half
    const int gate = row_local >> 6; // 0..3 (i,f,g,o)
    const int u_local = row_local & 63;
    const int row_global = gate * HH + g * UPB + u_local;
    const int last = seq_m[b] - 1;
    // proj role (waves 4-7): s in [0,256); col g*64+(s>>2); k-quarter s&3
    const int s = tid - 256;
    const int pu = s >> 2;
    const int kq = s & 3;
    const int pcol = g * UPB + pu;

    __shared__ float hbuf[2][HH];   // double-buffered h (phase1 reads ^1)
    __shared__ float g_lds[RPB];
    __shared__ float x_lds[2 * TT];
    __shared__ float h_final[HH];   // boundary h vector (rows 127)

    for (int i = tid; i < TT; i += 512) {
        x_lds[i] = seq[b * TT + i];
        x_lds[TT + i] = target[b * TT + i];
    }

    // Whh row slice as 64 float2 pairs (same memory image as float4[32];
    // float4 loads fill 4 consecutive VGPRs = two aligned pairs, no moves).
    f32x2 w2[64];
    float bias_r, wih_r;
    auto loadw = [&](const float* Whh, const float* Wih,
                     const float* bih, const float* bhh) {
        const float4* wr = (const float4*)(Whh + row_global * HH + half * 128);
#pragma unroll
        for (int i = 0; i < 32; ++i) ((float4*)w2)[i] = wr[i];
        bias_r = bih[row_global] + bhh[row_global];
        wih_r = Wih[row_global];
    };
    loadw(Whh_e, Wih_e, bih_e, bhh_e);

    float4 pw[16];
    float pb = 0.f;
    auto loadp = [&](const float* W, const float* bias) {
        const float4* src = (const float4*)(W + pcol * HH + kq * 64);
#pragma unroll
        for (int i = 0; i < 16; ++i) pw[i] = src[i];
        pb = bias[pcol];
    };
    if (tid >= 256) loadp(We, be);

    // plain proj dot: static offsets, no extra address VALU (R12-proven)
    auto projdot = [&](const float* hsrc) -> float {
        const float4* hp = (const float4*)(hsrc + kq * 64);
        float pa = 0.f;
#pragma unroll
        for (int i = 0; i < 16; ++i) {
            float4 hv = hp[i];
            pa = fmaf(pw[i].x, hv.x, pa);
            pa = fmaf(pw[i].y, hv.y, pa);
            pa = fmaf(pw[i].z, hv.z, pa);
            pa = fmaf(pw[i].w, hv.w, pa);
        }
        pa += __shfl_xor(pa, 1);
        pa += __shfl_xor(pa, 2);  // 4 k-quarters combined
        return pa + pb;
    };

    if (tid < 64) {  // h(-1) = 0 lives in buffer 1
        ((float4*)hbuf[1])[tid] = make_float4(0.f, 0.f, 0.f, 0.f);
    }
    __syncthreads();

    float c = 0.f, c_saved = 0.f, h_saved = 0.f;

    for (int t = 0; t < 2 * TT; ++t) {
        const int phase = t >> 7;  // 0 = encoder, 1 = decoder
        const int tt = t & 127;
        const float x = x_lds[t];
        const int rb = (t & 1) ^ 1;  // buffer holding h(t-1)

        // ---- phase 1 (all 8 waves): gate-row dot, pk_fma (2 FMA/inst) ----
        const float4* h4 = ((const float4*)hbuf[rb]) + half * 32;
        f32x2 acc0 = {0.f, 0.f}, acc1 = {0.f, 0.f};
#pragma unroll
        for (int i = 0; i < 32; ++i) {
            f32x2 hv2[2];
            *(float4*)hv2 = h4[i];  // one ds_read_b128, two aligned pairs
            asm("v_pk_fma_f32 %0, %2, %3, %0\n\t"
                "v_pk_fma_f32 %1, %4, %5, %1"
                : "+v"(acc0), "+v"(acc1)
                : "v"(w2[2 * i]), "v"(hv2[0]), "v"(w2[2 * i + 1]), "v"(hv2[1]));
        }
        float acc = (acc0.x + acc1.x) + (acc0.y + acc1.y);
        acc += __shfl_xor(acc, 1);  // combine the two k-halves
        float gv = acc + bias_r + x * wih_r;  // bias/Wih folded off serial path
        if (half == 0) g_lds[row_local] = gv;
        bar_lds();  // (A) gates visible; hbuf[t&1] free to write

        // ---- phase 2 (wave 0): minimal serial segment ----
        if (tid < 64) {
            float gi = g_lds[tid];
            float gf = g_lds[64 + tid];
            float gg = g_lds[128 + tid];
            float go = g_lds[192 + tid];
            float si = sigmoid_f(gi);
            float sf = sigmoid_f(gf);
            float tg = tanh_f(gg);
            float so = sigmoid_f(go);
            c = sf * c + si * tg;
            float h = so * tanh_f(c);
            const int ug = g * UPB + tid;
            // publish FIRST: the only VMEM op on wave 0's pre-barrier drain
            unsigned long long pkt =
                ((unsigned long long)(unsigned)(t + 1) << 32) | __float_as_uint(h);
            __hip_atomic_store(&mbox[(t & 1) * BB * HH + b * HH + ug], pkt,
                               __ATOMIC_RELAXED, AGENT);
            if (phase == 0 && tt == last) {
                c_saved = c;
                h_saved = h;
                unsigned long long spkt =
                    (1ull << 32) | (unsigned long long)__float_as_uint(h);
                __hip_atomic_store(&hsave[b * HH + ug], spkt, __ATOMIC_RELAXED, AGENT);
            }
            hbuf[t & 1][ug] = (t == TT - 1) ? h_saved : h;
        }

        // ---- phase 3 (waves 1..3): ring poll of partners' tagged h ----
        if (tid >= 64 && tid < 256) {
            const int p = (g + (tid >> 6)) & 3;  // partner slice 1..3 away
            const int lane = tid & 63;
            const int ppu = p * UPB + lane;
            unsigned long long* src;
            unsigned want;
            if (t == TT - 1) {
                src = &hsave[b * HH + ppu];
                want = 1u;
            } else {
                src = &mbox[(t & 1) * BB * HH + b * HH + ppu];
                want = (unsigned)(t + 1);
            }
            unsigned long long pv;
            {
                unsigned long long r0 = AL(src);
                unsigned long long r1 = AL(src);
                unsigned long long r2 = AL(src);
                unsigned long long r3 = AL(src);
                unsigned long long r4 = AL(src);
                unsigned long long r5 = AL(src);
                for (;;) {
                    if ((unsigned)(r0 >> 32) == want) { pv = r0; break; }
                    r0 = AL(src);
                    if ((unsigned)(r1 >> 32) == want) { pv = r1; break; }
                    r1 = AL(src);
                    if ((unsigned)(r2 >> 32) == want) { pv = r2; break; }
                    r2 = AL(src);
                    if ((unsigned)(r3 >> 32) == want) { pv = r3; break; }
                    r3 = AL(src);
                    if ((unsigned)(r4 >> 32) == want) { pv = r4; break; }
                    r4 = AL(src);
                    if ((unsigned)(r5 >> 32) == want) { pv = r5; break; }
                    r5 = AL(src);
                }
            }
            hbuf[t & 1][ppu] = __uint_as_float((unsigned)pv);
        }

        // ---- proj (waves 4..7): e2/d2 row t-1, hidden in the poll window --
        if (tid >= 256 && t >= 1) {
            const float* hsrc = (t == TT) ? h_final : hbuf[rb];
            float pv = projdot(hsrc);
            if (kq == 0) {
                if (t <= TT)
                    e2[(b * TT + (t - 1)) * HH + pcol] = pv;
                else
                    d2[(b * TT + (t - 1 - TT)) * HH + pcol] = pv;
            }
        }
        // at the enc boundary, recover full h(TT-1) (tag TT) into h_final
        if (tid >= 256 && t == TT - 1) {
            unsigned long long* src = &mbox[((TT - 1) & 1) * BB * HH + b * HH + s];
            const unsigned want = (unsigned)TT;
            unsigned long long r0 = AL(src);
            unsigned long long r1 = AL(src);
            unsigned long long pv;
            for (;;) {
                if ((unsigned)(r0 >> 32) == want) { pv = r0; break; }
                r0 = AL(src);
                if ((unsigned)(r1 >> 32) == want) { pv = r1; break; }
                r1 = AL(src);
            }
            h_final[s] = __uint_as_float((unsigned)pv);
        }
        if (tid >= 256 && t == TT) loadp(Wd, bd);

        bar_lds();  // (B) hbuf[t&1] complete for next step

        if (t == TT - 1) {  // encoder -> decoder transition
            loadw(Whh_d, Wih_d, bih_d, bhh_d);
            c = c_saved;
        }
    }

    // ---- post-loop: d2 row TT-1 from h(2TT-1) (tag 2TT) ----
    if (tid >= 256) {
        unsigned long long* src = &mbox[((2 * TT - 1) & 1) * BB * HH + b * HH + s];
        const unsigned want = (unsigned)(2 * TT);
        unsigned long long r0 = AL(src);
        unsigned long long r1 = AL(src);
        unsigned long long pv;
        for (;;) {
            if ((unsigned)(r0 >> 32) == want) { pv = r0; break; }
            r0 = AL(src);
            if ((unsigned)(r1 >> 32) == want) { pv = r1; break; }
            r1 = AL(src);
        }
        h_final[s] = __uint_as_float((unsigned)pv);
    }
    __syncthreads();
    if (tid >= 256) {
        float pv = projdot(h_final);
        if (kq == 0) d2[(b * TT + (TT - 1)) * HH + pcol] = pv;
    }
}

// ---------------------------------------------------------------------------
// Attention scores: p = tanh(e2_j + d2_i) . v  for a 32x32 (i,j) tile.
// grid = 512 = b(32) x it(4) x jt(4); block = 256; 4x i-register-blocked.
// ---------------------------------------------------------------------------
#define EPAD 260  // float4-aligned LDS row stride
__global__ __launch_bounds__(256) void attn_p_kernel(
    const float* __restrict__ e2, const float* __restrict__ d2,
    const float* __restrict__ vv, float* __restrict__ p_ws) {
    __shared__ float e2c[32][EPAD];
    __shared__ float d2t[32][EPAD];
    __shared__ float v_lds[HH];

    const int blk = blockIdx.x;
    const int b = blk >> 4;
    const int i0 = ((blk >> 2) & 3) * 32;
    const int j0 = (blk & 3) * 32;
    const int tid = threadIdx.x;
    const int jl = tid & 31, ig = tid >> 5;

    if (tid < 64) *(float4*)&v_lds[tid * 4] = ((const float4*)vv)[tid];
    for (int idx = tid; idx < 32 * 64; idx += 256) {
        int r = idx >> 6, q = idx & 63;
        *(float4*)&d2t[r][q * 4] = ((const float4*)(d2 + (b * TT + i0 + r) * HH))[q];
        *(float4*)&e2c[r][q * 4] = ((const float4*)(e2 + (b * TT + j0 + r) * HH))[q];
    }
    __syncthreads();

    float a0 = 0.f, a1 = 0.f, a2 = 0.f, a3 = 0.f;
    for (int h = 0; h < HH; h += 4) {
        float4 ev = *(const float4*)&e2c[jl][h];
        float4 vx = *(const float4*)&v_lds[h];
        float4 d0 = *(const float4*)&d2t[ig * 4 + 0][h];
        float4 d1 = *(const float4*)&d2t[ig * 4 + 1][h];
        float4 d2v = *(const float4*)&d2t[ig * 4 + 2][h];
        float4 d3 = *(const float4*)&d2t[ig * 4 + 3][h];
        a0 = fmaf(tanh_f(ev.x + d0.x), vx.x, a0);
        a0 = fmaf(tanh_f(ev.y + d0.y), vx.y, a0);
        a0 = fmaf(tanh_f(ev.z + d0.z), vx.z, a0);
        a0 = fmaf(tanh_f(ev.w + d0.w), vx.w, a0);
        a1 = fmaf(tanh_f(ev.x + d1.x), vx.x, a1);
        a1 = fmaf(tanh_f(ev.y + d1.y), vx.y, a1);
        a1 = fmaf(tanh_f(ev.z + d1.z), vx.z, a1);
        a1 = fmaf(tanh_f(ev.w + d1.w), vx.w, a1);
        a2 = fmaf(tanh_f(ev.x + d2v.x), vx.x, a2);
        a2 = fmaf(tanh_f(ev.y + d2v.y), vx.y, a2);
        a2 = fmaf(tanh_f(ev.z + d2v.z), vx.z, a2);
        a2 = fmaf(tanh_f(ev.w + d2v.w), vx.w, a2);
        a3 = fmaf(tanh_f(ev.x + d3.x), vx.x, a3);
        a3 = fmaf(tanh_f(ev.y + d3.y), vx.y, a3);
        a3 = fmaf(tanh_f(ev.z + d3.z), vx.z, a3);
        a3 = fmaf(tanh_f(ev.w + d3.w), vx.w, a3);
    }
    float* pr = p_ws + (b * TT + i0 + ig * 4) * TT + j0 + jl;
    pr[0 * TT] = a0;
    pr[1 * TT] = a1;
    pr[2 * TT] = a2;
    pr[3 * TT] = a3;
}

// ---------------------------------------------------------------------------
// Softmax over j with mask (memory-bound finisher).
// grid = 256 = b(32) x 8 row-tiles (16 rows); block = 256 (16 rows x 16 lanes).
// ---------------------------------------------------------------------------
__global__ __launch_bounds__(256) void attn_sm_kernel(
    const float* __restrict__ p_ws, const float* __restrict__ seq,
    float* __restrict__ out) {
    const int blk = blockIdx.x;
    const int b = blk >> 3;
    const int r0 = (blk & 7) * 16;
    const int tid = threadIdx.x;
    const int r = tid >> 4, l16 = tid & 15;
    const int row = (b * TT + r0 + r) * TT;

    float xr[8];
    float m = -1e30f;
#pragma unroll
    for (int k = 0; k < 8; ++k) {
        const int j = l16 + 16 * k;
        float x = p_ws[row + j];
        float sv = (j == 0) ? 0.1f : seq[b * TT + j];
        if (sv == 0.f) x -= 1000.f;
        xr[k] = x;
        m = fmaxf(m, x);
    }
#pragma unroll
    for (int o = 8; o >= 1; o >>= 1) m = fmaxf(m, __shfl_xor(m, o));
    float s = 0.f;
#pragma unroll
    for (int k = 0; k < 8; ++k) {
        xr[k] = __expf(xr[k] - m);
        s += xr[k];
    }
#pragma unroll
    for (int o = 8; o >= 1; o >>= 1) s += __shfl_xor(s, o);
    float inv = rcp_f(s);
#pragma unroll
    for (int k = 0; k < 8; ++k) out[row + l16 + 16 * k] = xr[k] * inv;
}

// ---------------------------------------------------------------------------
extern "C" void kernel_launch(void* const* d_in, const int* in_sizes, int n_in,
                              void* d_out, int out_size, void* d_ws, size_t ws_size,
                              hipStream_t stream) {
    const float* seq = (const float*)d_in[0];
    const int* seq_m = (const int*)d_in[1];
    const float* target = (const float*)d_in[2];
    const float* Wih_e = (const float*)d_in[3];
    const float* Whh_e = (const float*)d_in[4];
    const float* bih_e = (const float*)d_in[5];
    const float* bhh_e = (const float*)d_in[6];
    const float* Wih_d = (const float*)d_in[7];
    const float* Whh_d = (const float*)d_in[8];
    const float* bih_d = (const float*)d_in[9];
    const float* bhh_d = (const float*)d_in[10];
    const float* We = (const float*)d_in[11];
    const float* be = (const float*)d_in[12];
    const float* Wd = (const float*)d_in[13];
    const float* bd = (const float*)d_in[14];
    const float* vv = (const float*)d_in[15];

    float* ws = (float*)d_ws;
    const size_t SZ_ED = (size_t)BB * TT * HH;  // 1,048,576 floats
    float* e2 = ws;
    float* d2 = e2 + SZ_ED;
    float* p_ws = d2 + SZ_ED;                               // [B][128][128]
    unsigned long long* mbox =
        (unsigned long long*)(p_ws + (size_t)BB * TT * TT);  // [2][B][H]
    unsigned long long* hsave = mbox + 2 * BB * HH;          // [B][H]

    const size_t needed = (2 * SZ_ED + (size_t)BB * TT * TT) * sizeof(float) +
                          3 * BB * HH * sizeof(unsigned long long);
    if (ws_size < needed) return;

    hipMemsetAsync(mbox, 0, 3 * BB * HH * sizeof(unsigned long long), stream);
    lstm_kernel<<<BB * G4, 512, 0, stream>>>(seq, seq_m, target, Wih_e, Whh_e, bih_e,
                                             bhh_e, Wih_d, Whh_d, bih_d, bhh_d, We,
                                             be, Wd, bd, e2, d2, mbox, hsave);
    attn_p_kernel<<<512, 256, 0, stream>>>(e2, d2, vv, p_ws);
    attn_sm_kernel<<<256, 256, 0, stream>>>(p_ws, seq, (float*)d_out);
}

// Round 4
// 599.192 us; speedup vs baseline: 1.3664x; 1.0650x over previous
//
#include <hip/hip_runtime.h>
#include <hip/hip_bf16.h>

// Problem constants
#define BB 32    // batch
#define TT 128   // T_E == T_D
#define HH 256   // hidden
#define G4 4     // blocks per batch for LSTM
#define UPB 64   // units per LSTM slice (256/4)
#define RPB 256  // gate rows per LSTM slice (4 gates * 64 units)

#define AGENT __HIP_MEMORY_SCOPE_AGENT
#define AL(p) __hip_atomic_load((p), __ATOMIC_RELAXED, AGENT)

__device__ __forceinline__ float rcp_f(float x) { return __builtin_amdgcn_rcpf(x); }
__device__ __forceinline__ float sigmoid_f(float x) {
    return rcp_f(1.f + __expf(-x));  // ~1e-7 rel err vs 7e-3 threshold
}
__device__ __forceinline__ float tanh_f(float x) {
    float e = __expf(2.f * x);
    return 1.f - 2.f * rcp_f(e + 1.f);
}

// ---------------------------------------------------------------------------
// LSTM + fused projections — R19 = exact R15 structure (best measured: 484us)
// + XCD-coloring of the communication ring.
// grid = 128; block = 512 = 8 waves.
// R19 change: block index remap so all 4 slices of a batch land on the SAME
// XCD (round-robin dispatch: XCD = blockIdx % 8). Old: blk = g*32+b -> slices
// of batch b on 4 different XCDs, mbox ring through L3. New:
//   blk = (b%8) + 8*g + 32*(b/8)   =>   blk%8 == b%8 for all 4 slices.
// If agent-scope relaxed atomics are serviced in the shared per-XCD L2, the
// store->load RTT on the serial path drops ~2000+ -> ~500-800 cy.
// Measured ledger:
//   R12 plain proj (4-way-conflicted): lstm 545us
//   R13 pw[runtime idx]: scratch demotion, 1449us  -> static offsets only
//   R14 rotated address: conflict-free but +addr-VALU in slot, 645us
//   R15: lstm 484us (BEST)  |  R16 lgkmcnt-only barrier: 485us (NULL ->
//        vmcnt drain never on critical path)
//   R17 gate-colocation (no barA): 706us — act/publish on every wave. REVERT.
//   R18 pk_fma dot: 589us — v_pk_fma_f32 is NOT faster f32 on gfx950 (157TF
//        spec IS the scalar v_fma rate); asm also broke scheduling. REVERT.
// Conclusion so far: critical path = inter-block h-exchange RTT (~4540 cy/
// step vs ~850 cy dot+act). Attack the RTT, not the slots.
// ---------------------------------------------------------------------------
__global__ __launch_bounds__(512, 2) void lstm_kernel(
    const float* __restrict__ seq,     // [B][128]
    const int* __restrict__ seq_m,     // [B]
    const float* __restrict__ target,  // [B][128]
    const float* __restrict__ Wih_e,   // [1024]
    const float* __restrict__ Whh_e,   // [1024][256]
    const float* __restrict__ bih_e, const float* __restrict__ bhh_e,
    const float* __restrict__ Wih_d, const float* __restrict__ Whh_d,
    const float* __restrict__ bih_d, const float* __restrict__ bhh_d,
    const float* __restrict__ We, const float* __restrict__ be,
    const float* __restrict__ Wd, const float* __restrict__ bd,
    float* __restrict__ e2,  // [B][128][256]
    float* __restrict__ d2,  // [B][128][256]
    unsigned long long* __restrict__ mbox,   // [2][B][256] tagged h packets
    unsigned long long* __restrict__ hsave)  // [B][256] tag-1 enc state @ last
{
    const int blk = blockIdx.x;
    // R19 XCD-coloring decode: blk = (b%8) + 8*g + 32*(b/8)
    const int b = (blk & 7) | ((blk >> 5) << 3);  // batch 0..31
    const int g = (blk >> 3) & 3;                 // slice 0..3
    const int tid = threadIdx.x;
    const int row_local = tid >> 1;  // 0..255
    const int half = tid & 1;        // k-half
    const int gate = row_local >> 6; // 0..3 (i,f,g,o)
    const int u_local = row_local & 63;
    const int row_global = gate * HH + g * UPB + u_local;
    const int last = seq_m[b] - 1;
    // proj role (waves 4-7): s in [0,256); col g*64+(s>>2); k-quarter s&3
    const int s = tid - 256;
    const int pu = s >> 2;
    const int kq = s & 3;
    const int pcol = g * UPB + pu;

    __shared__ float hbuf[2][HH];   // double-buffered h (phase1 reads ^1)
    __shared__ float g_lds[RPB];
    __shared__ float x_lds[2 * TT];
    __shared__ float h_final[HH];   // boundary h vector (rows 127)

    for (int i = tid; i < TT; i += 512) {
        x_lds[i] = seq[b * TT + i];
        x_lds[TT + i] = target[b * TT + i];
    }

    float4 w[32];
    float bias_r, wih_r;
    auto loadw = [&](const float* Whh, const float* Wih,
                     const float* bih, const float* bhh) {
        const float4* wr = (const float4*)(Whh + row_global * HH + half * 128);
#pragma unroll
        for (int i = 0; i < 32; ++i) w[i] = wr[i];
        bias_r = bih[row_global] + bhh[row_global];
        wih_r = Wih[row_global];
    };
    loadw(Whh_e, Wih_e, bih_e, bhh_e);

    float4 pw[16];
    float pb = 0.f;
    auto loadp = [&](const float* W, const float* bias) {
        const float4* src = (const float4*)(W + pcol * HH + kq * 64);
#pragma unroll
        for (int i = 0; i < 16; ++i) pw[i] = src[i];
        pb = bias[pcol];
    };
    if (tid >= 256) loadp(We, be);

    // plain proj dot: static offsets, no extra address VALU (R12-proven)
    auto projdot = [&](const float* hsrc) -> float {
        const float4* hp = (const float4*)(hsrc + kq * 64);
        float pa = 0.f;
#pragma unroll
        for (int i = 0; i < 16; ++i) {
            float4 hv = hp[i];
            pa = fmaf(pw[i].x, hv.x, pa);
            pa = fmaf(pw[i].y, hv.y, pa);
            pa = fmaf(pw[i].z, hv.z, pa);
            pa = fmaf(pw[i].w, hv.w, pa);
        }
        pa += __shfl_xor(pa, 1);
        pa += __shfl_xor(pa, 2);  // 4 k-quarters combined
        return pa + pb;
    };

    if (tid < 64) {  // h(-1) = 0 lives in buffer 1
        ((float4*)hbuf[1])[tid] = make_float4(0.f, 0.f, 0.f, 0.f);
    }
    __syncthreads();

    float c = 0.f, c_saved = 0.f, h_saved = 0.f;

    for (int t = 0; t < 2 * TT; ++t) {
        const int phase = t >> 7;  // 0 = encoder, 1 = decoder
        const int tt = t & 127;
        const float x = x_lds[t];
        const int rb = (t & 1) ^ 1;  // buffer holding h(t-1)

        // ---- phase 1 (all 8 waves): gate-row dot over own 128-wide slice --
        const float4* h4 = ((const float4*)hbuf[rb]) + half * 32;
        float4 a4 = make_float4(0.f, 0.f, 0.f, 0.f);
#pragma unroll
        for (int i = 0; i < 32; ++i) {
            float4 hv = h4[i];
            a4.x = fmaf(w[i].x, hv.x, a4.x);
            a4.y = fmaf(w[i].y, hv.y, a4.y);
            a4.z = fmaf(w[i].z, hv.z, a4.z);
            a4.w = fmaf(w[i].w, hv.w, a4.w);
        }
        float acc = (a4.x + a4.y) + (a4.z + a4.w);
        acc += __shfl_xor(acc, 1);  // combine the two k-halves
        float gv = acc + bias_r + x * wih_r;  // bias/Wih folded off serial path
        if (half == 0) g_lds[row_local] = gv;
        __syncthreads();  // (A) gates visible; hbuf[t&1] free to write

        // ---- phase 2 (wave 0): minimal serial segment ----
        if (tid < 64) {
            float gi = g_lds[tid];
            float gf = g_lds[64 + tid];
            float gg = g_lds[128 + tid];
            float go = g_lds[192 + tid];
            float si = sigmoid_f(gi);
            float sf = sigmoid_f(gf);
            float tg = tanh_f(gg);
            float so = sigmoid_f(go);
            c = sf * c + si * tg;
            float h = so * tanh_f(c);
            const int ug = g * UPB + tid;
            // publish FIRST: the only VMEM op on wave 0's pre-barrier drain
            unsigned long long pkt =
                ((unsigned long long)(unsigned)(t + 1) << 32) | __float_as_uint(h);
            __hip_atomic_store(&mbox[(t & 1) * BB * HH + b * HH + ug], pkt,
                               __ATOMIC_RELAXED, AGENT);
            if (phase == 0 && tt == last) {
                c_saved = c;
                h_saved = h;
                unsigned long long spkt =
                    (1ull << 32) | (unsigned long long)__float_as_uint(h);
                __hip_atomic_store(&hsave[b * HH + ug], spkt, __ATOMIC_RELAXED, AGENT);
            }
            hbuf[t & 1][ug] = (t == TT - 1) ? h_saved : h;
        }

        // ---- phase 3 (waves 1..3): ring poll of partners' tagged h ----
        if (tid >= 64 && tid < 256) {
            const int p = (g + (tid >> 6)) & 3;  // partner slice 1..3 away
            const int lane = tid & 63;
            const int ppu = p * UPB + lane;
            unsigned long long* src;
            unsigned want;
            if (t == TT - 1) {
                src = &hsave[b * HH + ppu];
                want = 1u;
            } else {
                src = &mbox[(t & 1) * BB * HH + b * HH + ppu];
                want = (unsigned)(t + 1);
            }
            unsigned long long pv;
            {
                unsigned long long r0 = AL(src);
                unsigned long long r1 = AL(src);
                unsigned long long r2 = AL(src);
                unsigned long long r3 = AL(src);
                for (;;) {
                    if ((unsigned)(r0 >> 32) == want) { pv = r0; break; }
                    r0 = AL(src);
                    if ((unsigned)(r1 >> 32) == want) { pv = r1; break; }
                    r1 = AL(src);
                    if ((unsigned)(r2 >> 32) == want) { pv = r2; break; }
                    r2 = AL(src);
                    if ((unsigned)(r3 >> 32) == want) { pv = r3; break; }
                    r3 = AL(src);
                }
            }
            hbuf[t & 1][ppu] = __uint_as_float((unsigned)pv);
        }

        // ---- proj (waves 4..7): e2/d2 row t-1, hidden in the poll window --
        if (tid >= 256 && t >= 1) {
            const float* hsrc = (t == TT) ? h_final : hbuf[rb];
            float pv = projdot(hsrc);
            if (kq == 0) {
                if (t <= TT)
                    e2[(b * TT + (t - 1)) * HH + pcol] = pv;
                else
                    d2[(b * TT + (t - 1 - TT)) * HH + pcol] = pv;
            }
        }
        // at the enc boundary, recover full h(TT-1) (tag TT) into h_final
        if (tid >= 256 && t == TT - 1) {
            unsigned long long* src = &mbox[((TT - 1) & 1) * BB * HH + b * HH + s];
            const unsigned want = (unsigned)TT;
            unsigned long long r0 = AL(src);
            unsigned long long r1 = AL(src);
            unsigned long long pv;
            for (;;) {
                if ((unsigned)(r0 >> 32) == want) { pv = r0; break; }
                r0 = AL(src);
                if ((unsigned)(r1 >> 32) == want) { pv = r1; break; }
                r1 = AL(src);
            }
            h_final[s] = __uint_as_float((unsigned)pv);
        }
        if (tid >= 256 && t == TT) loadp(Wd, bd);

        __syncthreads();  // (B) hbuf[t&1] complete for next step

        if (t == TT - 1) {  // encoder -> decoder transition
            loadw(Whh_d, Wih_d, bih_d, bhh_d);
            c = c_saved;
        }
    }

    // ---- post-loop: d2 row TT-1 from h(2TT-1) (tag 2TT) ----
    if (tid >= 256) {
        unsigned long long* src = &mbox[((2 * TT - 1) & 1) * BB * HH + b * HH + s];
        const unsigned want = (unsigned)(2 * TT);
        unsigned long long r0 = AL(src);
        unsigned long long r1 = AL(src);
        unsigned long long pv;
        for (;;) {
            if ((unsigned)(r0 >> 32) == want) { pv = r0; break; }
            r0 = AL(src);
            if ((unsigned)(r1 >> 32) == want) { pv = r1; break; }
            r1 = AL(src);
        }
        h_final[s] = __uint_as_float((unsigned)pv);
    }
    __syncthreads();
    if (tid >= 256) {
        float pv = projdot(h_final);
        if (kq == 0) d2[(b * TT + (TT - 1)) * HH + pcol] = pv;
    }
}

// ---------------------------------------------------------------------------
// Attention scores: p = tanh(e2_j + d2_i) . v  for a 32x32 (i,j) tile.
// grid = 512 = b(32) x it(4) x jt(4); block = 256; 4x i-register-blocked.
// ---------------------------------------------------------------------------
#define EPAD 260  // float4-aligned LDS row stride
__global__ __launch_bounds__(256) void attn_p_kernel(
    const float* __restrict__ e2, const float* __restrict__ d2,
    const float* __restrict__ vv, float* __restrict__ p_ws) {
    __shared__ float e2c[32][EPAD];
    __shared__ float d2t[32][EPAD];
    __shared__ float v_lds[HH];

    const int blk = blockIdx.x;
    const int b = blk >> 4;
    const int i0 = ((blk >> 2) & 3) * 32;
    const int j0 = (blk & 3) * 32;
    const int tid = threadIdx.x;
    const int jl = tid & 31, ig = tid >> 5;

    if (tid < 64) *(float4*)&v_lds[tid * 4] = ((const float4*)vv)[tid];
    for (int idx = tid; idx < 32 * 64; idx += 256) {
        int r = idx >> 6, q = idx & 63;
        *(float4*)&d2t[r][q * 4] = ((const float4*)(d2 + (b * TT + i0 + r) * HH))[q];
        *(float4*)&e2c[r][q * 4] = ((const float4*)(e2 + (b * TT + j0 + r) * HH))[q];
    }
    __syncthreads();

    float a0 = 0.f, a1 = 0.f, a2 = 0.f, a3 = 0.f;
    for (int h = 0; h < HH; h += 4) {
        float4 ev = *(const float4*)&e2c[jl][h];
        float4 vx = *(const float4*)&v_lds[h];
        float4 d0 = *(const float4*)&d2t[ig * 4 + 0][h];
        float4 d1 = *(const float4*)&d2t[ig * 4 + 1][h];
        float4 d2v = *(const float4*)&d2t[ig * 4 + 2][h];
        float4 d3 = *(const float4*)&d2t[ig * 4 + 3][h];
        a0 = fmaf(tanh_f(ev.x + d0.x), vx.x, a0);
        a0 = fmaf(tanh_f(ev.y + d0.y), vx.y, a0);
        a0 = fmaf(tanh_f(ev.z + d0.z), vx.z, a0);
        a0 = fmaf(tanh_f(ev.w + d0.w), vx.w, a0);
        a1 = fmaf(tanh_f(ev.x + d1.x), vx.x, a1);
        a1 = fmaf(tanh_f(ev.y + d1.y), vx.y, a1);
        a1 = fmaf(tanh_f(ev.z + d1.z), vx.z, a1);
        a1 = fmaf(tanh_f(ev.w + d1.w), vx.w, a1);
        a2 = fmaf(tanh_f(ev.x + d2v.x), vx.x, a2);
        a2 = fmaf(tanh_f(ev.y + d2v.y), vx.y, a2);
        a2 = fmaf(tanh_f(ev.z + d2v.z), vx.z, a2);
        a2 = fmaf(tanh_f(ev.w + d2v.w), vx.w, a2);
        a3 = fmaf(tanh_f(ev.x + d3.x), vx.x, a3);
        a3 = fmaf(tanh_f(ev.y + d3.y), vx.y, a3);
        a3 = fmaf(tanh_f(ev.z + d3.z), vx.z, a3);
        a3 = fmaf(tanh_f(ev.w + d3.w), vx.w, a3);
    }
    float* pr = p_ws + (b * TT + i0 + ig * 4) * TT + j0 + jl;
    pr[0 * TT] = a0;
    pr[1 * TT] = a1;
    pr[2 * TT] = a2;
    pr[3 * TT] = a3;
}

// ---------------------------------------------------------------------------
// Softmax over j with mask (memory-bound finisher).
// grid = 256 = b(32) x 8 row-tiles (16 rows); block = 256 (16 rows x 16 lanes).
// ---------------------------------------------------------------------------
__global__ __launch_bounds__(256) void attn_sm_kernel(
    const float* __restrict__ p_ws, const float* __restrict__ seq,
    float* __restrict__ out) {
    const int blk = blockIdx.x;
    const int b = blk >> 3;
    const int r0 = (blk & 7) * 16;
    const int tid = threadIdx.x;
    const int r = tid >> 4, l16 = tid & 15;
    const int row = (b * TT + r0 + r) * TT;

    float xr[8];
    float m = -1e30f;
#pragma unroll
    for (int k = 0; k < 8; ++k) {
        const int j = l16 + 16 * k;
        float x = p_ws[row + j];
        float sv = (j == 0) ? 0.1f : seq[b * TT + j];
        if (sv == 0.f) x -= 1000.f;
        xr[k] = x;
        m = fmaxf(m, x);
    }
#pragma unroll
    for (int o = 8; o >= 1; o >>= 1) m = fmaxf(m, __shfl_xor(m, o));
    float s = 0.f;
#pragma unroll
    for (int k = 0; k < 8; ++k) {
        xr[k] = __expf(xr[k] - m);
        s += xr[k];
    }
#pragma unroll
    for (int o = 8; o >= 1; o >>= 1) s += __shfl_xor(s, o);
    float inv = rcp_f(s);
#pragma unroll
    for (int k = 0; k < 8; ++k) out[row + l16 + 16 * k] = xr[k] * inv;
}

// ---------------------------------------------------------------------------
extern "C" void kernel_launch(void* const* d_in, const int* in_sizes, int n_in,
                              void* d_out, int out_size, void* d_ws, size_t ws_size,
                              hipStream_t stream) {
    const float* seq = (const float*)d_in[0];
    const int* seq_m = (const int*)d_in[1];
    const float* target = (const float*)d_in[2];
    const float* Wih_e = (const float*)d_in[3];
    const float* Whh_e = (const float*)d_in[4];
    const float* bih_e = (const float*)d_in[5];
    const float* bhh_e = (const float*)d_in[6];
    const float* Wih_d = (const float*)d_in[7];
    const float* Whh_d = (const float*)d_in[8];
    const float* bih_d = (const float*)d_in[9];
    const float* bhh_d = (const float*)d_in[10];
    const float* We = (const float*)d_in[11];
    const float* be = (const float*)d_in[12];
    const float* Wd = (const float*)d_in[13];
    const float* bd = (const float*)d_in[14];
    const float* vv = (const float*)d_in[15];

    float* ws = (float*)d_ws;
    const size_t SZ_ED = (size_t)BB * TT * HH;  // 1,048,576 floats
    float* e2 = ws;
    float* d2 = e2 + SZ_ED;
    float* p_ws = d2 + SZ_ED;                               // [B][128][128]
    unsigned long long* mbox =
        (unsigned long long*)(p_ws + (size_t)BB * TT * TT);  // [2][B][H]
    unsigned long long* hsave = mbox + 2 * BB * HH;          // [B][H]

    const size_t needed = (2 * SZ_ED + (size_t)BB * TT * TT) * sizeof(float) +
                          3 * BB * HH * sizeof(unsigned long long);
    if (ws_size < needed) return;

    hipMemsetAsync(mbox, 0, 3 * BB * HH * sizeof(unsigned long long), stream);
    lstm_kernel<<<BB * G4, 512, 0, stream>>>(seq, seq_m, target, Wih_e, Whh_e, bih_e,
                                             bhh_e, Wih_d, Whh_d, bih_d, bhh_d, We,
                                             be, Wd, bd, e2, d2, mbox, hsave);
    attn_p_kernel<<<512, 256, 0, stream>>>(e2, d2, vv, p_ws);
    attn_sm_kernel<<<256, 256, 0, stream>>>(p_ws, seq, (float*)d_out);
}